// Round 4
// baseline (649.333 us; speedup 1.0000x reference)
//
#include <hip/hip_runtime.h>
#include <math.h>

#define AFWD 0.999f
#define EPS  1e-5f

constexpr int B      = 32;
constexpr int HW     = 64 * 64;      // 4096 spatial positions per sample
constexpr int C      = 256;          // channels
constexpr int CQ     = C / 4;        // 64 channel-quads (float4)
constexpr int CHUNKS = 32;           // spatial chunks per sample
constexpr int RPC    = HW / CHUNKS;  // 128 rows per chunk
constexpr int GRID   = B * CHUNKS;   // 1024 blocks = 4/CU, all co-resident

// Native vector type for __builtin_nontemporal_store (HIP float4 is a class).
typedef float nfloat4 __attribute__((ext_vector_type(4)));

// ---------------------------------------------------------------------------
// Single-dispatch fused Online-Norm forward (cooperative, all blocks resident).
//   Block b: t = b&31 (interleaved so each CU hosts mixed-t blocks),
//            chunk = b>>5. Each block handles exactly ONE (t,chunk):
//   Phase A: sum/sumsq over its 128-row chunk -> atomicAdd accum[t],
//            release-publish done[t].   (publish BEFORE any wait!)
//   Wait:    tid0 spins until done[tt]==CHUNKS for all tt<t (only smaller t,
//            so deadlock-free under full co-residency).
//   Scan:    redundant <=31-step EMA from finalized accum (cheap, L2-hit).
//   Phase C: re-read chunk (L3-resident from phase A; NT stores don't evict),
//            normalize, non-temporal store (out never re-read).
//   vs the 2-kernel version: no inter-kernel drain, one less dispatch, and
//   early-t blocks start the write stream while late-t blocks still sum.
// ---------------------------------------------------------------------------
__global__ void __launch_bounds__(256, 4)
fused2(const float4* __restrict__ x4,
       const float*  __restrict__ mu0,
       const float*  __restrict__ var0,
       float*        __restrict__ accum_s,
       float*        __restrict__ accum_q,
       int*          __restrict__ done,
       float4*       __restrict__ out4) {
    const int b     = blockIdx.x;
    const int t     = b & 31;
    const int chunk = b >> 5;
    const int tid   = threadIdx.x;
    const int cq    = tid & 63;      // channel quad
    const int rs    = tid >> 6;      // row sub-lane

    const int base = (t * HW + chunk * RPC) * CQ;  // max 8.4M float4, int-safe

    // ---- Phase A: partial sums over the chunk (fully coalesced, 1KB/wave/instr)
    float4 s = make_float4(0.f, 0.f, 0.f, 0.f);
    float4 q = make_float4(0.f, 0.f, 0.f, 0.f);
    #pragma unroll 4
    for (int k = 0; k < RPC / 4; ++k) {
        const float4 v = x4[base + (rs + k * 4) * CQ + cq];
        s.x += v.x; s.y += v.y; s.z += v.z; s.w += v.w;
        q.x += v.x * v.x; q.y += v.y * v.y; q.z += v.z * v.z; q.w += v.w * v.w;
    }

    __shared__ float4 ls[256];                    // 4 KB
    __shared__ float4 lq[256];                    // 4 KB
    ls[tid] = s;
    lq[tid] = q;
    __syncthreads();
    {
        // Thread tid owns channel c = tid; word index k*256+c -> bank c%32,
        // conflict-free.
        const int c2 = tid >> 2, comp = tid & 3;
        float ss = 0.f, qq = 0.f;
        #pragma unroll
        for (int k = 0; k < 4; ++k) {
            ss += ((const float*)&ls[k * 64 + c2])[comp];
            qq += ((const float*)&lq[k * 64 + c2])[comp];
        }
        atomicAdd(&accum_s[t * C + tid], ss);
        atomicAdd(&accum_q[t * C + tid], qq);
    }
    __threadfence();                 // order this thread's adds to agent scope
    __syncthreads();                 // all 256 threads' adds issued+fenced

    if (tid == 0) {
        __hip_atomic_fetch_add(&done[t], 1, __ATOMIC_RELEASE,
                               __HIP_MEMORY_SCOPE_AGENT);
        // Wait for every sample < t to be fully accumulated (publish-first
        // ordering above makes this deadlock-free with all blocks resident).
        for (int tt = 0; tt < t; ++tt)
            while (__hip_atomic_load(&done[tt], __ATOMIC_ACQUIRE,
                                     __HIP_MEMORY_SCOPE_AGENT) < CHUNKS)
                __builtin_amdgcn_s_sleep(4);
    }
    __syncthreads();                 // deps satisfied for whole block

    // ---- Scan: EMA carry through samples 0..t-1 for channel c = tid
    float mu  = mu0[tid];
    float var = var0[tid];
    const float inv = 1.0f / (float)HW;
    for (int tt = 0; tt < t; ++tt) {
        const float S = __hip_atomic_load(&accum_s[tt * C + tid],
                                          __ATOMIC_RELAXED,
                                          __HIP_MEMORY_SCOPE_AGENT);
        const float Q = __hip_atomic_load(&accum_q[tt * C + tid],
                                          __ATOMIC_RELAXED,
                                          __HIP_MEMORY_SCOPE_AGENT);
        const float m  = S * inv;
        const float vt = Q * inv - m * m;
        const float d  = m - mu;
        var = AFWD * var + (1.0f - AFWD) * vt + AFWD * (1.0f - AFWD) * d * d;
        mu  = mu + (1.0f - AFWD) * d;
    }

    __shared__ float smu[C];         // 1 KB
    __shared__ float srs[C];         // 1 KB
    smu[tid] = mu;
    srs[tid] = 1.0f / sqrtf(var + EPS);
    __syncthreads();

    // ---- Phase C: re-read chunk (L3-hit), normalize, NT-store
    const float4 m4 = ((const float4*)smu)[cq];
    const float4 r4 = ((const float4*)srs)[cq];
    #pragma unroll 4
    for (int k = 0; k < RPC / 4; ++k) {
        const int i = base + (rs + k * 4) * CQ + cq;
        const float4 v = x4[i];
        nfloat4 o;
        o.x = (v.x - m4.x) * r4.x;
        o.y = (v.y - m4.y) * r4.y;
        o.z = (v.z - m4.z) * r4.z;
        o.w = (v.w - m4.w) * r4.w;
        __builtin_nontemporal_store(o, (nfloat4*)&out4[i]);
    }
}

// ---------------------------------------------------------------------------
// Host launcher. Workspace: accum_s[B*C] + accum_q[B*C] floats + done[B] ints.
// ---------------------------------------------------------------------------
extern "C" void kernel_launch(void* const* d_in, const int* in_sizes, int n_in,
                              void* d_out, int out_size, void* d_ws, size_t ws_size,
                              hipStream_t stream) {
    const float4* x4   = (const float4*)d_in[0];
    const float*  mu0  = (const float*)d_in[1];
    const float*  var0 = (const float*)d_in[2];
    // d_in[3] (u0), d_in[4] (v0): backward-only controls, unused in fwd.
    float4* out4 = (float4*)d_out;

    float* accum_s = (float*)d_ws;
    float* accum_q = accum_s + B * C;
    int*   done    = (int*)(accum_q + B * C);

    // Zero accumulators + done flags (harness poisons d_ws each call).
    (void)hipMemsetAsync(d_ws, 0,
                         (size_t)(2 * B * C) * sizeof(float) + B * sizeof(int),
                         stream);

    void* args[] = {(void*)&x4, (void*)&mu0, (void*)&var0,
                    (void*)&accum_s, (void*)&accum_q, (void*)&done, (void*)&out4};
    (void)hipLaunchCooperativeKernel((const void*)fused2, dim3(GRID),
                                     dim3(256), args, 0, stream);
}

// Round 5
// 327.024 us; speedup vs baseline: 1.9856x; 1.9856x over previous
//
#include <hip/hip_runtime.h>
#include <math.h>

#define AFWD 0.999f
#define EPS  1e-5f

constexpr int B      = 32;
constexpr int HW     = 64 * 64;      // 4096 spatial positions per sample
constexpr int C      = 256;          // channels
constexpr int CQ     = C / 4;        // 64 channel-quads (float4)
constexpr int CHUNKS = 32;           // spatial chunks per sample
constexpr int RPC    = HW / CHUNKS;  // 128 rows per chunk
constexpr int GRID   = B * CHUNKS;   // 1024 blocks = 4/CU, all co-resident

// Native vector type for __builtin_nontemporal_store (HIP float4 is a class).
typedef float nfloat4 __attribute__((ext_vector_type(4)));

// ---------------------------------------------------------------------------
// Fence-free single-dispatch fused Online-Norm forward (cooperative).
//
// Round-4 lesson: agent-scope ACQUIRE loads lower to buffer_inv (L2-wide
// invalidate) and __threadfence to buffer_wbl2 (L2-wide writeback) on gfx950's
// non-coherent per-XCD L2s; spinning with them creates a cache-maintenance
// storm that stalls the whole memory system (540us at 0.9% VALU). This
// version uses ONLY coherence-point operations:
//   - accum published via atomicAdd (device-scope RMW, executes at the
//     coherence point -> globally visible, NO fence needed);
//   - __syncthreads' built-in s_waitcnt vmcnt(0) drains the adds before tid0
//     issues the done[t] fetch_add -> publish ordering without any fence;
//   - spin + accum reads are RELAXED agent-scope loads (sc-flagged, read the
//     coherence point directly, NO buffer_inv per poll).
// Block b: t = b&31 (mixed t per CU), chunk = b>>5; one (t,chunk) per block.
// Deadlock-free: publish-before-wait, waits only on strictly smaller t.
// ---------------------------------------------------------------------------
__global__ void __launch_bounds__(256, 4)
fused3(const float4* __restrict__ x4,
       const float*  __restrict__ mu0,
       const float*  __restrict__ var0,
       float*        __restrict__ accum_s,
       float*        __restrict__ accum_q,
       int*          __restrict__ done,
       float4*       __restrict__ out4) {
    const int b     = blockIdx.x;
    const int t     = b & 31;
    const int chunk = b >> 5;
    const int tid   = threadIdx.x;
    const int cq    = tid & 63;      // channel quad
    const int rs    = tid >> 6;      // row sub-lane

    const int base = (t * HW + chunk * RPC) * CQ;  // max 8.4M float4, int-safe

    // ---- Phase A: partial sums over the chunk (coalesced, 1KB/wave/instr)
    float4 s = make_float4(0.f, 0.f, 0.f, 0.f);
    float4 q = make_float4(0.f, 0.f, 0.f, 0.f);
    #pragma unroll 4
    for (int k = 0; k < RPC / 4; ++k) {
        const float4 v = x4[base + (rs + k * 4) * CQ + cq];
        s.x += v.x; s.y += v.y; s.z += v.z; s.w += v.w;
        q.x += v.x * v.x; q.y += v.y * v.y; q.z += v.z * v.z; q.w += v.w * v.w;
    }

    __shared__ float4 ls[256];                    // 4 KB
    __shared__ float4 lq[256];                    // 4 KB
    ls[tid] = s;
    lq[tid] = q;
    __syncthreads();
    {
        // Thread tid owns channel c = tid; word index k*256+c -> bank c%32,
        // conflict-free.
        const int c2 = tid >> 2, comp = tid & 3;
        float ss = 0.f, qq = 0.f;
        #pragma unroll
        for (int k = 0; k < 4; ++k) {
            ss += ((const float*)&ls[k * 64 + c2])[comp];
            qq += ((const float*)&lq[k * 64 + c2])[comp];
        }
        // Device-scope RMWs: execute at the coherence point, no fence needed.
        atomicAdd(&accum_s[t * C + tid], ss);
        atomicAdd(&accum_q[t * C + tid], qq);
    }
    // __syncthreads emits s_waitcnt vmcnt(0) before s_barrier: all 256
    // threads' atomic adds have COMPLETED at the coherence point past here.
    __syncthreads();

    if (tid == 0) {
        // Publish (relaxed RMW — ordering provided by the vmcnt(0) drain above).
        __hip_atomic_fetch_add(&done[t], 1, __ATOMIC_RELAXED,
                               __HIP_MEMORY_SCOPE_AGENT);
        // Spin with RELAXED loads: sc-flagged read of the coherence point,
        // no L2 invalidate per poll.
        for (int tt = 0; tt < t; ++tt)
            while (__hip_atomic_load(&done[tt], __ATOMIC_RELAXED,
                                     __HIP_MEMORY_SCOPE_AGENT) < CHUNKS)
                __builtin_amdgcn_s_sleep(4);
    }
    __syncthreads();                 // deps satisfied for whole block

    // ---- Scan: EMA carry through samples 0..t-1 for channel c = tid.
    // Relaxed agent loads read the coherence point (values final since each
    // done[tt] hit CHUNKS only after all its adds completed). 1-deep prefetch
    // hides the ~700-cycle coherence-point latency.
    float mu  = mu0[tid];
    float var = var0[tid];
    const float inv = 1.0f / (float)HW;
    if (t > 0) {
        float S = __hip_atomic_load(&accum_s[tid], __ATOMIC_RELAXED,
                                    __HIP_MEMORY_SCOPE_AGENT);
        float Q = __hip_atomic_load(&accum_q[tid], __ATOMIC_RELAXED,
                                    __HIP_MEMORY_SCOPE_AGENT);
        for (int tt = 0; tt < t; ++tt) {
            float Sn = 0.f, Qn = 0.f;
            if (tt + 1 < t) {
                Sn = __hip_atomic_load(&accum_s[(tt + 1) * C + tid],
                                       __ATOMIC_RELAXED,
                                       __HIP_MEMORY_SCOPE_AGENT);
                Qn = __hip_atomic_load(&accum_q[(tt + 1) * C + tid],
                                       __ATOMIC_RELAXED,
                                       __HIP_MEMORY_SCOPE_AGENT);
            }
            const float m  = S * inv;
            const float vt = Q * inv - m * m;
            const float d  = m - mu;
            var = AFWD * var + (1.0f - AFWD) * vt
                + AFWD * (1.0f - AFWD) * d * d;
            mu  = mu + (1.0f - AFWD) * d;
            S = Sn; Q = Qn;
        }
    }

    __shared__ float smu[C];         // 1 KB
    __shared__ float srs[C];         // 1 KB
    smu[tid] = mu;
    srs[tid] = 1.0f / sqrtf(var + EPS);
    __syncthreads();

    // ---- Phase C: re-read chunk (L3-resident from phase A; NT stores below
    // don't evict it), normalize, non-temporal store (out never re-read).
    const float4 m4 = ((const float4*)smu)[cq];
    const float4 r4 = ((const float4*)srs)[cq];
    #pragma unroll 4
    for (int k = 0; k < RPC / 4; ++k) {
        const int i = base + (rs + k * 4) * CQ + cq;
        const float4 v = x4[i];
        nfloat4 o;
        o.x = (v.x - m4.x) * r4.x;
        o.y = (v.y - m4.y) * r4.y;
        o.z = (v.z - m4.z) * r4.z;
        o.w = (v.w - m4.w) * r4.w;
        __builtin_nontemporal_store(o, (nfloat4*)&out4[i]);
    }
}

// ---------------------------------------------------------------------------
// Host launcher. Workspace: accum_s[B*C] + accum_q[B*C] floats + done[B] ints.
// ---------------------------------------------------------------------------
extern "C" void kernel_launch(void* const* d_in, const int* in_sizes, int n_in,
                              void* d_out, int out_size, void* d_ws, size_t ws_size,
                              hipStream_t stream) {
    const float4* x4   = (const float4*)d_in[0];
    const float*  mu0  = (const float*)d_in[1];
    const float*  var0 = (const float*)d_in[2];
    // d_in[3] (u0), d_in[4] (v0): backward-only controls, unused in fwd.
    float4* out4 = (float4*)d_out;

    float* accum_s = (float*)d_ws;
    float* accum_q = accum_s + B * C;
    int*   done    = (int*)(accum_q + B * C);

    // Zero accumulators + done flags (harness poisons d_ws each call).
    (void)hipMemsetAsync(d_ws, 0,
                         (size_t)(2 * B * C) * sizeof(float) + B * sizeof(int),
                         stream);

    void* args[] = {(void*)&x4, (void*)&mu0, (void*)&var0,
                    (void*)&accum_s, (void*)&accum_q, (void*)&done, (void*)&out4};
    (void)hipLaunchCooperativeKernel((const void*)fused3, dim3(GRID),
                                     dim3(256), args, 0, stream);
}

// Round 6
// 260.110 us; speedup vs baseline: 2.4964x; 1.2573x over previous
//
#include <hip/hip_runtime.h>
#include <math.h>

#define AFWD 0.999f
#define EPS  1e-5f

constexpr int B  = 32;
constexpr int HW = 64 * 64;      // 4096 spatial positions per sample
constexpr int C  = 256;          // channels
constexpr int CQ = C / 4;        // 64 channel-quads (float4)
constexpr int CHUNKS = 32;       // spatial chunks per sample
constexpr int RPC = HW / CHUNKS; // 128 rows per chunk

// Native vector type for __builtin_nontemporal_store (HIP float4 is a class).
typedef float nfloat4 __attribute__((ext_vector_type(4)));

// ---------------------------------------------------------------------------
// Kernel 1: per-(t,chunk) partial sums -> atomicAdd into packed accum[t][c]
// = {sum, sumsq} (float2). Only samples 0..30: sample 31's sums are never
// consumed (out_31 uses stats through sample 30), so skip them.
// Block 256 thr: cq = tid&63 (channel quad), rs = tid>>6 (row sub-lane).
// Wave reads 64 consecutive float4 = 1KB, fully coalesced. Regular (cached)
// loads leave x resident in L3 (134 MB < 256 MB) for k2's re-read.
// ---------------------------------------------------------------------------
__global__ void __launch_bounds__(256)
k1_partial(const float4* __restrict__ x4,
           float* __restrict__ accum) {   // packed [B][C][2]
    const int blk   = blockIdx.x;
    const int t     = blk >> 5;           // 0..30
    const int chunk = blk & 31;
    const int tid   = threadIdx.x;
    const int cq    = tid & 63;
    const int rs    = tid >> 6;

    const long base = (long)(t * HW + chunk * RPC) * CQ;

    float4 s = make_float4(0.f, 0.f, 0.f, 0.f);
    float4 q = make_float4(0.f, 0.f, 0.f, 0.f);
    #pragma unroll 4
    for (int k = 0; k < RPC / 4; ++k) {
        const float4 v = x4[base + (long)(rs + k * 4) * CQ + cq];
        s.x += v.x; s.y += v.y; s.z += v.z; s.w += v.w;
        q.x += v.x * v.x; q.y += v.y * v.y; q.z += v.z * v.z; q.w += v.w * v.w;
    }

    __shared__ float4 ls[256];
    __shared__ float4 lq[256];
    ls[tid] = s;
    lq[tid] = q;
    __syncthreads();

    // Thread tid owns channel c = tid. Word index read = k*256 + c -> bank c%32,
    // conflict-free.
    const int cq2  = tid >> 2;
    const int comp = tid & 3;
    float ssum = 0.f, qsum = 0.f;
    #pragma unroll
    for (int k = 0; k < 4; ++k) {
        ssum += ((const float*)&ls[k * 64 + cq2])[comp];
        qsum += ((const float*)&lq[k * 64 + cq2])[comp];
    }
    // Device-scope fire-and-forget RMWs; kernel boundary is the barrier.
    atomicAdd(&accum[(t * C + tid) * 2 + 0], ssum);
    atomicAdd(&accum[(t * C + tid) * 2 + 1], qsum);
}

// ---------------------------------------------------------------------------
// Kernel 2: per-block redundant EMA scan (<=31 steps, float2 loads, L2-hit),
// then normalize this block's chunk. x re-read is L3-resident (left there by
// k1); out stored NON-TEMPORALLY so the 134 MB write stream does not evict x
// from L2/L3 mid-kernel (out is never re-read).
// ---------------------------------------------------------------------------
__global__ void __launch_bounds__(256)
k2_norm(const float4* __restrict__ x4,
        const float* __restrict__ mu0,
        const float* __restrict__ var0,
        const float2* __restrict__ accum,   // packed [B][C] of {sum, sumsq}
        float4* __restrict__ out4) {
    const int blk   = blockIdx.x;
    const int t     = blk >> 5;
    const int chunk = blk & 31;
    const int tid   = threadIdx.x;

    // Scan for channel c = tid: carry after samples 0..t-1.
    float mu  = mu0[tid];
    float var = var0[tid];
    const float inv = 1.0f / (float)HW;
    for (int tt = 0; tt < t; ++tt) {
        const float2 sq = accum[tt * C + tid];   // one 8B L2-hit load per step
        const float m  = sq.x * inv;
        const float vt = sq.y * inv - m * m;
        const float d  = m - mu;
        var = AFWD * var + (1.0f - AFWD) * vt + AFWD * (1.0f - AFWD) * d * d;
        mu  = mu + (1.0f - AFWD) * d;
    }

    __shared__ float smu[C];
    __shared__ float srs[C];
    smu[tid] = mu;
    srs[tid] = 1.0f / sqrtf(var + EPS);
    __syncthreads();

    const int cq = tid & 63;
    const int rs = tid >> 6;
    const float4 mu4 = ((const float4*)smu)[cq];
    const float4 rs4 = ((const float4*)srs)[cq];

    const long base = (long)(t * HW + chunk * RPC) * CQ;
    #pragma unroll 4
    for (int k = 0; k < RPC / 4; ++k) {
        const long i = base + (long)(rs + k * 4) * CQ + cq;
        const float4 v = x4[i];
        nfloat4 o;
        o.x = (v.x - mu4.x) * rs4.x;
        o.y = (v.y - mu4.y) * rs4.y;
        o.z = (v.z - mu4.z) * rs4.z;
        o.w = (v.w - mu4.w) * rs4.w;
        __builtin_nontemporal_store(o, (nfloat4*)&out4[i]);
    }
}

// ---------------------------------------------------------------------------
// Host launcher. Workspace: packed accum [B][C] float2 = 64KB (rows 0..30 used).
// ---------------------------------------------------------------------------
extern "C" void kernel_launch(void* const* d_in, const int* in_sizes, int n_in,
                              void* d_out, int out_size, void* d_ws, size_t ws_size,
                              hipStream_t stream) {
    const float4* x4   = (const float4*)d_in[0];
    const float*  mu0  = (const float*)d_in[1];
    const float*  var0 = (const float*)d_in[2];
    // d_in[3] (u0), d_in[4] (v0): backward-only controls, unused in fwd.
    float4* out4 = (float4*)d_out;

    float* accum = (float*)d_ws;

    // Zero only the consumed rows 0..30 (harness poisons d_ws each call).
    (void)hipMemsetAsync(accum, 0, (size_t)(B - 1) * C * 2 * sizeof(float),
                         stream);

    // Samples 0..30 only: sample 31's sums are never read.
    k1_partial<<<dim3((B - 1) * CHUNKS), 256, 0, stream>>>(x4, accum);

    k2_norm<<<dim3(B * CHUNKS), 256, 0, stream>>>(x4, mu0, var0,
                                                  (const float2*)accum, out4);
}